// Round 4
// baseline (237.004 us; speedup 1.0000x reference)
//
#include <hip/hip_runtime.h>

#define N_NODES 100000
#define D 128          // feature dim
#define K 16           // neighbors
#define MB 16          // nodes per block (6250 blocks exact)

typedef __attribute__((ext_vector_type(8))) short bf16x8;
typedef __attribute__((ext_vector_type(4))) float f32x4;
typedef __attribute__((ext_vector_type(2))) float f32x2;

// LDS map (bytes):
//   [0,     32768) sNeigh : 16 neighbors x [16 nodes x 128 B], rows chunk-rotated by 16*m
//   [32768, 37120) sSelf  : 16 x 136 bf16 (272 B rows, padded)
//   [37120, 38208) sIdx   : 16 x 17 int (padded)
//   zb overlay @0 : 16 x 132 f32 (epilogue staging)
#define LDS_BYTES 38208

__device__ __forceinline__ unsigned short f2bf(float f) {
    union { float f; unsigned u; } v; v.f = f;
    unsigned u = v.u;
    return (unsigned short)((u + 0x7fffu + ((u >> 16) & 1u)) >> 16);  // RNE
}
__device__ __forceinline__ unsigned pk4(float a, float b, float c, float d) {
    int w = __builtin_amdgcn_cvt_pk_fp8_f32(a, b, 0, false);
    w = __builtin_amdgcn_cvt_pk_fp8_f32(c, d, w, true);
    return (unsigned)w;
}

// feats f32 -> fp8 table; Ws -> Wt (self half, bf16, [l][n][k<128]) + W8 (agg half *16, fp8, [l][n][k<128])
__global__ void cvt_all(const float* __restrict__ feats, const float* __restrict__ Ws,
                        unsigned* __restrict__ f8, unsigned short* __restrict__ Wt,
                        unsigned char* __restrict__ W8) {
    int tid = blockIdx.x * 256 + threadIdx.x;
    int i = tid * 16;
    if (i < N_NODES * D) {
        const float4* p = (const float4*)(feats + i);
        float4 v0 = p[0], v1 = p[1], v2 = p[2], v3 = p[3];
        uint4 o;
        o.x = pk4(v0.x, v0.y, v0.z, v0.w);
        o.y = pk4(v1.x, v1.y, v1.z, v1.w);
        o.z = pk4(v2.x, v2.y, v2.z, v2.w);
        o.w = pk4(v3.x, v3.y, v3.z, v3.w);
        *(uint4*)(f8 + i / 4) = o;
    }
    if (tid < 2 * D * D) {          // 32768
        int l = tid >> 14, r = tid & 16383;
        int n = r >> 7, k = r & 127;
        const float* Wl = Ws + l * (2 * D * D);
        Wt[tid] = f2bf(Wl[k * D + n]);                       // self rows 0..127
        int w = __builtin_amdgcn_cvt_pk_fp8_f32(Wl[(D + k) * D + n] * 16.f, 0.f, 0, false);
        W8[tid] = (unsigned char)(w & 0xff);                 // agg rows 128..255, x16
    }
}

// One layer: async fp8 gather -> LDS, K-concat fp8 MFMA (agg) + bf16 MFMA (self)
template <int LAYER>
__launch_bounds__(256, 4)
__global__ void sage_layer(const float* __restrict__ self_f32,
                           const unsigned short* __restrict__ self_bf,
                           const unsigned char* __restrict__ g8,
                           const int* __restrict__ idx,
                           const unsigned short* __restrict__ Wt,
                           const unsigned char* __restrict__ W8,
                           const float* __restrict__ bias,
                           unsigned short* __restrict__ h_out,
                           unsigned char* __restrict__ h8_out,
                           float* __restrict__ z_out) {
    __shared__ __align__(16) char sm[LDS_BYTES];
    unsigned short (*sSelf)[136] = (unsigned short (*)[136])(sm + 32768);
    int (*sIdx)[17] = (int (*)[17])(sm + 37120);
    float (*zb)[132] = (float (*)[132])sm;

    const int t = threadIdx.x;
    const int base = blockIdx.x * MB;
    const int lane = t & 63;
    const int wave = t >> 6;
    const int q = lane >> 4;
    const int nlo = lane & 15;

    // ---- stage indices (1 coalesced dword per thread) ----
    sIdx[t >> 4][t & 15] = idx[(size_t)base * K + t];

    // ---- self rows -> sSelf (bf16, padded stride 136) ----
    {
        int m = t >> 4, c = (t & 15) * 8;
        if (LAYER == 0) {
            const float4* sp = (const float4*)(self_f32 + (size_t)(base + m) * D + c);
            float4 a = sp[0], b = sp[1];
            unsigned w0 = (unsigned)f2bf(a.x) | ((unsigned)f2bf(a.y) << 16);
            unsigned w1 = (unsigned)f2bf(a.z) | ((unsigned)f2bf(a.w) << 16);
            unsigned w2 = (unsigned)f2bf(b.x) | ((unsigned)f2bf(b.y) << 16);
            unsigned w3 = (unsigned)f2bf(b.z) | ((unsigned)f2bf(b.w) << 16);
            *(uint4*)&sSelf[m][c] = make_uint4(w0, w1, w2, w3);
        } else {
            *(uint4*)&sSelf[m][c] = *(const uint4*)(self_bf + (size_t)(base + m) * D + c);
        }
    }
    __syncthreads();   // sIdx ready for gather

    // ---- async gather: raw fp8 rows -> sNeigh via global_load_lds (16 B/lane) ----
    // neighbor n tile: 16 nodes x 128 B contiguous; row m chunk-rotated by 16*m
#pragma unroll
    for (int nn = 0; nn < 4; ++nn) {
        int n = wave * 4 + nn;
#pragma unroll
        for (int j = 0; j < 2; ++j) {
            int m = j * 8 + (lane >> 3);
            int node = sIdx[m][n];
            int c = (((lane & 7) - m) << 4) & 127;   // rotated source chunk
            const void* gp = (const void*)(g8 + ((size_t)node << 7) + c);
            void* lp = (void*)(sm + n * 2048 + j * 1024);   // +lane*16 by HW
            __builtin_amdgcn_global_load_lds(
                (const __attribute__((address_space(1))) unsigned int*)gp,
                (__attribute__((address_space(3))) unsigned int*)lp, 16, 0, 0);
        }
    }

    // ---- B fragments (VGPR), overlap gather latency ----
    long b8[2][4];          // fp8 agg W, cols wave*32 + nt*16 + nlo
    bf16x8 bsf[2][4];       // bf16 self W
#pragma unroll
    for (int nt = 0; nt < 2; ++nt) {
        int col = wave * 32 + nt * 16 + nlo;
#pragma unroll
        for (int ksm = 0; ksm < 4; ++ksm) {
            b8[nt][ksm] = *(const long*)(W8 + (size_t)col * 128 + ksm * 32 + q * 8);
            bsf[nt][ksm] = *(const bf16x8*)(Wt + (size_t)col * 128 + ksm * 32 + q * 8);
        }
    }

    __syncthreads();   // drains global_load_lds (vmcnt) + LDS writes

    // ---- MFMA: agg K=2048 fp8 + self K=128 bf16 ----
    f32x4 aAgg0 = {}, aAgg1 = {}, aSelf0 = {}, aSelf1 = {};
#pragma unroll 8
    for (int ks = 0; ks < 64; ++ks) {
        int n = ks >> 2, ksm = ks & 3;
        int ro = (ksm * 32 + q * 8 + nlo * 16) & 127;
        long av = *(const long*)(sm + n * 2048 + nlo * 128 + ro);
        aAgg0 = __builtin_amdgcn_mfma_f32_16x16x32_fp8_fp8(av, b8[0][ksm], aAgg0, 0, 0, 0);
        aAgg1 = __builtin_amdgcn_mfma_f32_16x16x32_fp8_fp8(av, b8[1][ksm], aAgg1, 0, 0, 0);
    }
#pragma unroll
    for (int ks = 0; ks < 4; ++ks) {
        bf16x8 av = *(const bf16x8*)&sSelf[nlo][ks * 32 + q * 8];
        aSelf0 = __builtin_amdgcn_mfma_f32_16x16x32_bf16(av, bsf[0][ks], aSelf0, 0, 0, 0);
        aSelf1 = __builtin_amdgcn_mfma_f32_16x16x32_bf16(av, bsf[1][ks], aSelf1, 0, 0, 0);
    }

    // ---- epilogue: z = self + agg/256 + bias, staged via LDS for coalesced stores ----
    __syncthreads();   // all sNeigh reads done; safe to overlay zb
#pragma unroll
    for (int nt = 0; nt < 2; ++nt) {
        int col = wave * 32 + nt * 16 + nlo;
        float bv = bias[col];
        f32x4 vs = nt ? aSelf1 : aSelf0;
        f32x4 va = nt ? aAgg1 : aAgg0;
#pragma unroll
        for (int r = 0; r < 4; ++r)
            zb[q * 4 + r][col] = vs[r] + va[r] * (1.0f / 256.0f) + bv;
    }
    __syncthreads();
    {
        int m = t >> 4, c = (t & 15) * 8;
        float x[8];
        *(f32x4*)&x[0] = *(const f32x4*)&zb[m][c];
        *(f32x4*)&x[4] = *(const f32x4*)&zb[m][c + 4];
        size_t go = (size_t)(base + m) * D + c;
        if (LAYER == 1) {
            float4* zp = (float4*)(z_out + go);
            zp[0] = make_float4(x[0], x[1], x[2], x[3]);
            zp[1] = make_float4(x[4], x[5], x[6], x[7]);
        } else {
#pragma unroll
            for (int i = 0; i < 8; ++i) x[i] = x[i] > 0.f ? x[i] : 0.f;
            unsigned w0 = (unsigned)f2bf(x[0]) | ((unsigned)f2bf(x[1]) << 16);
            unsigned w1 = (unsigned)f2bf(x[2]) | ((unsigned)f2bf(x[3]) << 16);
            unsigned w2 = (unsigned)f2bf(x[4]) | ((unsigned)f2bf(x[5]) << 16);
            unsigned w3 = (unsigned)f2bf(x[6]) | ((unsigned)f2bf(x[7]) << 16);
            *(uint4*)(h_out + go) = make_uint4(w0, w1, w2, w3);
            uint2 o8;
            o8.x = pk4(x[0], x[1], x[2], x[3]);
            o8.y = pk4(x[4], x[5], x[6], x[7]);
            *(uint2*)(h8_out + go) = o8;
        }
    }
}

extern "C" void kernel_launch(void* const* d_in, const int* in_sizes, int n_in,
                              void* d_out, int out_size, void* d_ws, size_t ws_size,
                              hipStream_t stream) {
    const float* feats = (const float*)d_in[0];
    const int* neigh   = (const int*)d_in[1];
    const float* Ws    = (const float*)d_in[2];
    const float* bs    = (const float*)d_in[3];
    float* out = (float*)d_out;

    char* ws = (char*)d_ws;
    unsigned short* h1_bf  = (unsigned short*)(ws);               // 25,600,000 B
    unsigned char*  feats8 = (unsigned char*)(ws + 25600000);     // 12,800,000 B
    unsigned char*  h18    = (unsigned char*)(ws + 38400000);     // 12,800,000 B
    unsigned short* Wt     = (unsigned short*)(ws + 51200000);    //     65,536 B
    unsigned char*  W8     = (unsigned char*)(ws + 51265536);     //     32,768 B

    cvt_all<<<3125, 256, 0, stream>>>(feats, Ws, (unsigned*)feats8, Wt, W8);

    sage_layer<0><<<N_NODES / MB, 256, 0, stream>>>(
        feats, nullptr, feats8, neigh, Wt, W8, bs, h1_bf, h18, nullptr);
    sage_layer<1><<<N_NODES / MB, 256, 0, stream>>>(
        nullptr, h1_bf, h18, neigh + N_NODES * K, Wt + D * D, W8 + D * D, bs + D,
        nullptr, nullptr, out);
}

// Round 5
// 234.803 us; speedup vs baseline: 1.0094x; 1.0094x over previous
//
#include <hip/hip_runtime.h>

#define N_NODES 100000
#define D 128          // feature dim
#define K 16           // neighbors
#define CATK 256       // concat dim
#define MB 16          // nodes per block (6250 blocks exact)

typedef __attribute__((ext_vector_type(8))) short bf16x8;
typedef __attribute__((ext_vector_type(4))) float f32x4;
typedef __attribute__((ext_vector_type(2))) float f32x2;

// LDS map (bytes):
//   [0,     32768) sNeigh : [k=16][m=16][128 B] raw fp8 rows
//   [32768, 41216) cat    : 16 x 264 bf16 (self|agg, 528-B rows)  /  zb overlay 16 x 132 f32
#define LDS_BYTES 41216

__device__ __forceinline__ unsigned short f2bf(float f) {
    union { float f; unsigned u; } v; v.f = f;
    unsigned u = v.u;
    return (unsigned short)((u + 0x7fffu + ((u >> 16) & 1u)) >> 16);  // RNE
}
__device__ __forceinline__ unsigned pk4(float a, float b, float c, float d) {
    int w = __builtin_amdgcn_cvt_pk_fp8_f32(a, b, 0, false);
    w = __builtin_amdgcn_cvt_pk_fp8_f32(c, d, w, true);
    return (unsigned)w;
}
__device__ __forceinline__ void dec4(unsigned w, float* acc) {
    f32x2 lo = __builtin_amdgcn_cvt_pk_f32_fp8((int)w, false);
    f32x2 hi = __builtin_amdgcn_cvt_pk_f32_fp8((int)w, true);
    acc[0] += lo.x; acc[1] += lo.y; acc[2] += hi.x; acc[3] += hi.y;
}

// feats f32 -> fp8 table; Ws [2,256,128] f32 -> Wt [2,128,256] bf16 (transposed)
__global__ void cvt_all(const float* __restrict__ feats, const float* __restrict__ Ws,
                        unsigned* __restrict__ f8, unsigned short* __restrict__ Wt) {
    int tid = blockIdx.x * 256 + threadIdx.x;
    int i = tid * 16;
    if (i < N_NODES * D) {
        const float4* p = (const float4*)(feats + i);
        float4 v0 = p[0], v1 = p[1], v2 = p[2], v3 = p[3];
        uint4 o;
        o.x = pk4(v0.x, v0.y, v0.z, v0.w);
        o.y = pk4(v1.x, v1.y, v1.z, v1.w);
        o.z = pk4(v2.x, v2.y, v2.z, v2.w);
        o.w = pk4(v3.x, v3.y, v3.z, v3.w);
        *(uint4*)(f8 + i / 4) = o;
    }
    if (tid < 2 * CATK * D) {
        int l = tid / (CATK * D);
        int r = tid % (CATK * D);
        int n = r / CATK, k = r % CATK;
        Wt[tid] = f2bf(Ws[l * CATK * D + k * D + n]);
    }
}

// One layer: async fp8 gather -> LDS (zero VGPR round-trip), LDS decode+mean,
// bf16 MFMA K=256, staged epilogue.
template <int LAYER>
__launch_bounds__(256, 3)
__global__ void sage_layer(const float* __restrict__ self_f32,
                           const unsigned short* __restrict__ self_bf,
                           const unsigned char* __restrict__ g8,
                           const int* __restrict__ idx,
                           const unsigned short* __restrict__ Wt,
                           const float* __restrict__ bias,
                           unsigned short* __restrict__ h_out,
                           unsigned char* __restrict__ h8_out,
                           float* __restrict__ z_out) {
    __shared__ __align__(16) char sm[LDS_BYTES];
    unsigned short (*cat)[264] = (unsigned short (*)[264])(sm + 32768);
    float (*zb)[132] = (float (*)[132])(sm + 32768);

    const int t = threadIdx.x;
    const int base = blockIdx.x * MB;
    const int lane = t & 63;
    const int wave = t >> 6;
    const int q = lane >> 4;
    const int nlo = lane & 15;
    const int m = t >> 4;            // node (epilogue/decode/self mapping)
    const int c = (t & 15) * 8;      // 8-element column chunk

    // ---- 1. this wave's 8 gather-instr indices: (k = wave*4+nn, j half) ----
    int vidx[8];
#pragma unroll
    for (int nn = 0; nn < 4; ++nn)
#pragma unroll
        for (int j = 0; j < 2; ++j)
            vidx[nn * 2 + j] =
                idx[(size_t)(base + j * 8 + (lane >> 3)) * K + wave * 4 + nn];

    // ---- 2. B fragments (independent; overlap idx latency) ----
    bf16x8 bfrag[2][8];
#pragma unroll
    for (int nt = 0; nt < 2; ++nt) {
        int col = wave * 32 + nt * 16 + nlo;
        const unsigned short* wp = Wt + (size_t)col * CATK + q * 8;
#pragma unroll
        for (int ks = 0; ks < 8; ++ks)
            bfrag[nt][ks] = *(const bf16x8*)(wp + ks * 32);
    }

    // ---- 3. async gathers: 8 rows per instr (8 lanes/row, 16 B/lane) ----
#pragma unroll
    for (int nn = 0; nn < 4; ++nn)
#pragma unroll
        for (int j = 0; j < 2; ++j) {
            int node = vidx[nn * 2 + j];
            const void* gp = (const void*)(g8 + ((size_t)node << 7) + ((lane & 7) << 4));
            void* lp = (void*)(sm + (wave * 4 + nn) * 2048 + j * 1024);  // +lane*16 by HW
            __builtin_amdgcn_global_load_lds(
                (const __attribute__((address_space(1))) unsigned int*)gp,
                (__attribute__((address_space(3))) unsigned int*)lp, 16, 0, 0);
        }

    // ---- 4. self row -> cat[m][c..c+8) (bf16) ----
    if (LAYER == 0) {
        const float4* sp = (const float4*)(self_f32 + (size_t)(base + m) * D + c);
        float4 a = sp[0], b = sp[1];
        unsigned w0 = (unsigned)f2bf(a.x) | ((unsigned)f2bf(a.y) << 16);
        unsigned w1 = (unsigned)f2bf(a.z) | ((unsigned)f2bf(a.w) << 16);
        unsigned w2 = (unsigned)f2bf(b.x) | ((unsigned)f2bf(b.y) << 16);
        unsigned w3 = (unsigned)f2bf(b.z) | ((unsigned)f2bf(b.w) << 16);
        *(uint4*)&cat[m][c] = make_uint4(w0, w1, w2, w3);
    } else {
        *(uint4*)&cat[m][c] = *(const uint4*)(self_bf + (size_t)(base + m) * D + c);
    }

    __syncthreads();   // drains async gathers + LDS writes

    // ---- 5. decode + mean from LDS: 16 x ds_read_b64, linear, conflict-free ----
    {
        float acc[8];
#pragma unroll
        for (int i = 0; i < 8; ++i) acc[i] = 0.f;
#pragma unroll
        for (int k = 0; k < K; ++k) {
            uint2 v = *(const uint2*)(sm + k * 2048 + m * 128 + c);
            dec4(v.x, acc);
            dec4(v.y, acc + 4);
        }
        unsigned pk[4];
#pragma unroll
        for (int j = 0; j < 4; ++j)
            pk[j] = (unsigned)f2bf(acc[2 * j] * (1.f / 16.f)) |
                    ((unsigned)f2bf(acc[2 * j + 1] * (1.f / 16.f)) << 16);
        *(uint4*)&cat[m][D + c] = make_uint4(pk[0], pk[1], pk[2], pk[3]);
    }
    __syncthreads();

    // ---- 6. MFMA: [16 x 256] x [256 x 32/wave] ----
    f32x4 acc0 = {}, acc1 = {};
#pragma unroll
    for (int ks = 0; ks < 8; ++ks) {
        bf16x8 av = *(const bf16x8*)&cat[nlo][ks * 32 + q * 8];
        acc0 = __builtin_amdgcn_mfma_f32_16x16x32_bf16(av, bfrag[0][ks], acc0, 0, 0, 0);
        acc1 = __builtin_amdgcn_mfma_f32_16x16x32_bf16(av, bfrag[1][ks], acc1, 0, 0, 0);
    }

    // ---- 7. epilogue via LDS staging (zb overlays cat) ----
    __syncthreads();
#pragma unroll
    for (int nt = 0; nt < 2; ++nt) {
        int col = wave * 32 + nt * 16 + nlo;
        float bv = bias[col];
        f32x4 va = nt ? acc1 : acc0;
#pragma unroll
        for (int r = 0; r < 4; ++r)
            zb[q * 4 + r][col] = va[r] + bv;
    }
    __syncthreads();
    {
        float x[8];
        *(f32x4*)&x[0] = *(const f32x4*)&zb[m][c];
        *(f32x4*)&x[4] = *(const f32x4*)&zb[m][c + 4];
        size_t go = (size_t)(base + m) * D + c;
        if (LAYER == 1) {
            float4* zp = (float4*)(z_out + go);
            zp[0] = make_float4(x[0], x[1], x[2], x[3]);
            zp[1] = make_float4(x[4], x[5], x[6], x[7]);
        } else {
#pragma unroll
            for (int i = 0; i < 8; ++i) x[i] = x[i] > 0.f ? x[i] : 0.f;
            unsigned w0 = (unsigned)f2bf(x[0]) | ((unsigned)f2bf(x[1]) << 16);
            unsigned w1 = (unsigned)f2bf(x[2]) | ((unsigned)f2bf(x[3]) << 16);
            unsigned w2 = (unsigned)f2bf(x[4]) | ((unsigned)f2bf(x[5]) << 16);
            unsigned w3 = (unsigned)f2bf(x[6]) | ((unsigned)f2bf(x[7]) << 16);
            *(uint4*)(h_out + go) = make_uint4(w0, w1, w2, w3);
            uint2 o8;
            o8.x = pk4(x[0], x[1], x[2], x[3]);
            o8.y = pk4(x[4], x[5], x[6], x[7]);
            *(uint2*)(h8_out + go) = o8;
        }
    }
}

extern "C" void kernel_launch(void* const* d_in, const int* in_sizes, int n_in,
                              void* d_out, int out_size, void* d_ws, size_t ws_size,
                              hipStream_t stream) {
    const float* feats = (const float*)d_in[0];
    const int* neigh   = (const int*)d_in[1];
    const float* Ws    = (const float*)d_in[2];
    const float* bs    = (const float*)d_in[3];
    float* out = (float*)d_out;

    char* ws = (char*)d_ws;
    unsigned short* h1_bf  = (unsigned short*)(ws);               // 25,600,000 B
    unsigned char*  feats8 = (unsigned char*)(ws + 25600000);     // 12,800,000 B
    unsigned char*  h18    = (unsigned char*)(ws + 38400000);     // 12,800,000 B
    unsigned short* Wt     = (unsigned short*)(ws + 51200000);    //    131,072 B

    cvt_all<<<3125, 256, 0, stream>>>(feats, Ws, (unsigned*)feats8, Wt);

    sage_layer<0><<<N_NODES / MB, 256, 0, stream>>>(
        feats, nullptr, feats8, neigh, Wt, bs, h1_bf, h18, nullptr);
    sage_layer<1><<<N_NODES / MB, 256, 0, stream>>>(
        nullptr, h1_bf, h18, neigh + N_NODES * K, Wt + CATK * D, bs + D,
        nullptr, nullptr, out);
}

// Round 6
// 213.434 us; speedup vs baseline: 1.1104x; 1.1001x over previous
//
#include <hip/hip_runtime.h>

#define N_NODES 100000
#define D 128          // feature dim
#define K 16           // neighbors
#define CATK 256       // concat dim (2*D)
#define MB 32          // nodes per block
#define PAD 8
#define LDSW (CATK + PAD)   // 264 bf16 elems -> 528 B row stride
#define ZW 132              // z-staging row stride in floats (528 B)

typedef __attribute__((ext_vector_type(8))) short bf16x8;
typedef __attribute__((ext_vector_type(4))) float f32x4;
typedef __attribute__((ext_vector_type(2))) float f32x2;

__device__ __forceinline__ unsigned short f2bf(float f) {
    union { float f; unsigned u; } v; v.f = f;
    unsigned u = v.u;
    return (unsigned short)((u + 0x7fffu + ((u >> 16) & 1u)) >> 16);  // RNE
}

// pack 4 floats -> 4 fp8 e4m3 bytes
__device__ __forceinline__ unsigned pk4(float a, float b, float c, float d) {
    int w = __builtin_amdgcn_cvt_pk_fp8_f32(a, b, 0, false);
    w = __builtin_amdgcn_cvt_pk_fp8_f32(c, d, w, true);
    return (unsigned)w;
}

// decode 4 fp8 bytes, accumulate into acc[0..3]
__device__ __forceinline__ void dec4(unsigned w, float* acc) {
    f32x2 lo = __builtin_amdgcn_cvt_pk_f32_fp8((int)w, false);
    f32x2 hi = __builtin_amdgcn_cvt_pk_f32_fp8((int)w, true);
    acc[0] += lo.x; acc[1] += lo.y; acc[2] += hi.x; acc[3] += hi.y;
}

// feats f32 -> fp8 table; also Ws [2,256,128] f32 -> Wt [2,128,256] bf16 (transposed)
__global__ void cvt_all(const float* __restrict__ feats, const float* __restrict__ Ws,
                        unsigned* __restrict__ f8, unsigned short* __restrict__ Wt) {
    int tid = blockIdx.x * 256 + threadIdx.x;
    int i = tid * 16;
    if (i < N_NODES * D) {
        const float4* p = (const float4*)(feats + i);
        float4 v0 = p[0], v1 = p[1], v2 = p[2], v3 = p[3];
        uint4 o;
        o.x = pk4(v0.x, v0.y, v0.z, v0.w);
        o.y = pk4(v1.x, v1.y, v1.z, v1.w);
        o.z = pk4(v2.x, v2.y, v2.z, v2.w);
        o.w = pk4(v3.x, v3.y, v3.z, v3.w);
        *(uint4*)(f8 + i / 4) = o;
    }
    if (tid < 2 * CATK * D) {
        int l = tid / (CATK * D);
        int r = tid % (CATK * D);
        int n = r / CATK, k = r % CATK;
        Wt[tid] = f2bf(Ws[l * CATK * D + k * D + n]);
    }
}

// One GraphSAGE layer: gather(fp8)+mean+concat+GEMM(+bias)(+relu)
// LAYER==0: self from f32 feats; outputs h1 bf16 + h1 fp8
// LAYER==1: self from bf16 h1; outputs z f32
template <int LAYER>
__launch_bounds__(256)
__global__ void sage_layer(const float* __restrict__ self_f32,
                           const unsigned short* __restrict__ self_bf,
                           const unsigned char* __restrict__ g8,
                           const int* __restrict__ idx,
                           const unsigned short* __restrict__ Wt,
                           const float* __restrict__ bias,
                           unsigned short* __restrict__ h_out,
                           unsigned char* __restrict__ h8_out,
                           float* __restrict__ z_out) {
    __shared__ __align__(16) char smraw[MB * LDSW * 2];   // 16896 B, dual-purpose
    unsigned short (*cat)[LDSW] = (unsigned short (*)[LDSW])smraw;
    float (*zb)[ZW] = (float (*)[ZW])smraw;
    __shared__ int sIdx[MB][K];

    const int t = threadIdx.x;
    const int base = blockIdx.x * MB;
    const int lane = t & 63;
    const int wave = t >> 6;
    const int q = lane >> 4;
    const int nlo = lane & 15;

    // ---- stage neighbor indices (int4-vectorized) ----
    if (t < MB * K / 4)
        ((int4*)&sIdx[0][0])[t] = ((const int4*)(idx + base * K))[t];
    __syncthreads();

    // ---- gather(fp8) + mean + self + concat into LDS (bf16) ----
    {
        const int m = t >> 3;            // node in tile
        const int c = (t & 7) * 16;      // 16-element column slice
        const int node = base + m;

        // self part
        if (LAYER == 0) {
            const float4* sp = (const float4*)(self_f32 + (size_t)node * D + c);
            float sv[16];
            *(f32x4*)&sv[0]  = *(const f32x4*)&sp[0];
            *(f32x4*)&sv[4]  = *(const f32x4*)&sp[1];
            *(f32x4*)&sv[8]  = *(const f32x4*)&sp[2];
            *(f32x4*)&sv[12] = *(const f32x4*)&sp[3];
            unsigned w[8];
#pragma unroll
            for (int j = 0; j < 8; ++j)
                w[j] = (unsigned)f2bf(sv[2 * j]) | ((unsigned)f2bf(sv[2 * j + 1]) << 16);
            *(uint4*)&cat[m][c]     = make_uint4(w[0], w[1], w[2], w[3]);
            *(uint4*)&cat[m][c + 8] = make_uint4(w[4], w[5], w[6], w[7]);
        } else {
            const uint4* sp = (const uint4*)(self_bf + (size_t)node * D + c);
            *(uint4*)&cat[m][c]     = sp[0];
            *(uint4*)&cat[m][c + 8] = sp[1];
        }

        // neighbor mean from fp8 table (16 B = 16 elems per load)
        float acc[16];
#pragma unroll
        for (int i = 0; i < 16; ++i) acc[i] = 0.f;
#pragma unroll 4
        for (int k = 0; k < K; ++k) {
            uint4 u = *(const uint4*)(g8 + (size_t)sIdx[m][k] * D + c);
            dec4(u.x, acc + 0);
            dec4(u.y, acc + 4);
            dec4(u.z, acc + 8);
            dec4(u.w, acc + 12);
        }
        unsigned pk[8];
#pragma unroll
        for (int j = 0; j < 8; ++j) {
            unsigned short a = f2bf(acc[2 * j] * (1.f / 16.f));
            unsigned short b = f2bf(acc[2 * j + 1] * (1.f / 16.f));
            pk[j] = (unsigned)a | ((unsigned)b << 16);
        }
        *(uint4*)&cat[m][D + c]     = make_uint4(pk[0], pk[1], pk[2], pk[3]);
        *(uint4*)&cat[m][D + c + 8] = make_uint4(pk[4], pk[5], pk[6], pk[7]);
    }

    // ---- per-wave B fragments (32 output cols, K=256) in VGPRs ----
    bf16x8 bfrag[2][8];
#pragma unroll
    for (int ct = 0; ct < 2; ++ct) {
        int n = wave * 32 + ct * 16 + nlo;
        const unsigned short* wp = Wt + n * CATK + q * 8;
#pragma unroll
        for (int ks = 0; ks < 8; ++ks)
            bfrag[ct][ks] = *(const bf16x8*)(wp + ks * 32);
    }

    __syncthreads();

    // ---- MFMA: [32 x 256] x [256 x 32(this wave)] ----
    f32x4 acc00 = {}, acc01 = {}, acc10 = {}, acc11 = {};
#pragma unroll
    for (int ks = 0; ks < 8; ++ks) {
        bf16x8 a0 = *(const bf16x8*)&cat[nlo][ks * 32 + q * 8];
        bf16x8 a1 = *(const bf16x8*)&cat[16 + nlo][ks * 32 + q * 8];
        acc00 = __builtin_amdgcn_mfma_f32_16x16x32_bf16(a0, bfrag[0][ks], acc00, 0, 0, 0);
        acc01 = __builtin_amdgcn_mfma_f32_16x16x32_bf16(a0, bfrag[1][ks], acc01, 0, 0, 0);
        acc10 = __builtin_amdgcn_mfma_f32_16x16x32_bf16(a1, bfrag[0][ks], acc10, 0, 0, 0);
        acc11 = __builtin_amdgcn_mfma_f32_16x16x32_bf16(a1, bfrag[1][ks], acc11, 0, 0, 0);
    }

    // ---- stage z tile into LDS (reusing cat's memory), then vector stores ----
    __syncthreads();  // all A-fragment reads done; safe to overwrite
#pragma unroll
    for (int ct = 0; ct < 2; ++ct) {
        int col = wave * 32 + ct * 16 + nlo;
        float bv = bias[col];
        f32x4 v0 = (ct == 0) ? acc00 : acc01;
        f32x4 v1 = (ct == 0) ? acc10 : acc11;
#pragma unroll
        for (int r = 0; r < 4; ++r) {
            zb[q * 4 + r][col]      = v0[r] + bv;
            zb[16 + q * 4 + r][col] = v1[r] + bv;
        }
    }
    __syncthreads();
    {
        const int m = t >> 3;
        const int c = (t & 7) * 16;
        float x[16];
        *(f32x4*)&x[0]  = *(const f32x4*)&zb[m][c];
        *(f32x4*)&x[4]  = *(const f32x4*)&zb[m][c + 4];
        *(f32x4*)&x[8]  = *(const f32x4*)&zb[m][c + 8];
        *(f32x4*)&x[12] = *(const f32x4*)&zb[m][c + 12];
        size_t go = (size_t)(base + m) * D + c;
        if (LAYER == 1) {
            float4* zp = (float4*)(z_out + go);
            zp[0] = make_float4(x[0], x[1], x[2], x[3]);
            zp[1] = make_float4(x[4], x[5], x[6], x[7]);
            zp[2] = make_float4(x[8], x[9], x[10], x[11]);
            zp[3] = make_float4(x[12], x[13], x[14], x[15]);
        } else {
#pragma unroll
            for (int i = 0; i < 16; ++i) x[i] = x[i] > 0.f ? x[i] : 0.f;
            unsigned wb[8];
#pragma unroll
            for (int j = 0; j < 8; ++j)
                wb[j] = (unsigned)f2bf(x[2 * j]) | ((unsigned)f2bf(x[2 * j + 1]) << 16);
            uint4* hp = (uint4*)(h_out + go);
            hp[0] = make_uint4(wb[0], wb[1], wb[2], wb[3]);
            hp[1] = make_uint4(wb[4], wb[5], wb[6], wb[7]);
            uint4 o8;
            o8.x = pk4(x[0], x[1], x[2], x[3]);
            o8.y = pk4(x[4], x[5], x[6], x[7]);
            o8.z = pk4(x[8], x[9], x[10], x[11]);
            o8.w = pk4(x[12], x[13], x[14], x[15]);
            *(uint4*)(h8_out + go) = o8;
        }
    }
}

extern "C" void kernel_launch(void* const* d_in, const int* in_sizes, int n_in,
                              void* d_out, int out_size, void* d_ws, size_t ws_size,
                              hipStream_t stream) {
    const float* feats = (const float*)d_in[0];
    const int* neigh   = (const int*)d_in[1];
    const float* Ws    = (const float*)d_in[2];
    const float* bs    = (const float*)d_in[3];
    float* out = (float*)d_out;

    char* ws = (char*)d_ws;
    unsigned short* h1_bf  = (unsigned short*)(ws);                 // 25,600,000 B
    unsigned char*  feats8 = (unsigned char*)(ws + 25600000);       // 12,800,000 B
    unsigned char*  h18    = (unsigned char*)(ws + 38400000);       // 12,800,000 B
    unsigned short* Wt     = (unsigned short*)(ws + 51200000);      //    131,072 B

    cvt_all<<<3125, 256, 0, stream>>>(feats, Ws, (unsigned*)feats8, Wt);

    sage_layer<0><<<N_NODES / MB, 256, 0, stream>>>(
        feats, nullptr, feats8, neigh, Wt, bs, h1_bf, h18, nullptr);
    sage_layer<1><<<N_NODES / MB, 256, 0, stream>>>(
        nullptr, h1_bf, h18, neigh + N_NODES * K, Wt + CATK * D, bs + D,
        nullptr, nullptr, out);
}